// Round 9
// baseline (136.079 us; speedup 1.0000x reference)
//
#include <hip/hip_runtime.h>
#include <math.h>

#define SEQ 576
#define DIM 192
#define INNER 384
#define NHEAD 96
#define HS 24
#define WSZ 24
#define GIN 1152
#define GKS 4

// 1) fused LayerNorm + up-proj GEMM: x_inner = LN(x) @ up_w.T + up_b
//    grid (9,24): BM=64 x BN=32, 128 thr, 4x4/thread.
//    As[k][m^swz] swizzled (swz = 4*((k>>2)&15)), Bs[k][o^swz2] (swz2 = 4*((k>>2)&7)).
__global__ __launch_bounds__(128) void k_up(const float* __restrict__ x,
    const float* __restrict__ lnw, const float* __restrict__ lnb,
    const float* __restrict__ w, const float* __restrict__ b,
    float* __restrict__ out) {
  int m0 = blockIdx.x * 64, n0 = blockIdx.y * 32;
  __shared__ float As[DIM * 64];
  __shared__ float Bs[DIM * 32];
  __shared__ float mu[64], inv[64], ps[128];
  int t = threadIdx.x;
  for (int idx = t; idx < 64 * 48; idx += 128) {
    int r = idx / 48, k4 = idx % 48;
    float4 v = *(const float4*)&x[(m0 + r) * DIM + 4 * k4];
    int rw = r ^ (4 * (k4 & 15));
    As[(4 * k4 + 0) * 64 + rw] = v.x;
    As[(4 * k4 + 1) * 64 + rw] = v.y;
    As[(4 * k4 + 2) * 64 + rw] = v.z;
    As[(4 * k4 + 3) * 64 + rw] = v.w;
  }
  for (int idx = t; idx < 32 * 48; idx += 128) {
    int r = idx / 48, k4 = idx % 48;
    float4 v = *(const float4*)&w[(n0 + r) * DIM + 4 * k4];
    int rw = r ^ (4 * (k4 & 7));
    Bs[(4 * k4 + 0) * 32 + rw] = v.x;
    Bs[(4 * k4 + 1) * 32 + rw] = v.y;
    Bs[(4 * k4 + 2) * 32 + rw] = v.z;
    Bs[(4 * k4 + 3) * 32 + rw] = v.w;
  }
  __syncthreads();
  // LN stats: 2 threads per row
  {
    int r = t & 63, ph = t >> 6;
    float s_ = 0.f;
    #pragma unroll 8
    for (int k = ph * 96; k < ph * 96 + 96; ++k)
      s_ += As[k * 64 + (r ^ (4 * ((k >> 2) & 15)))];
    ps[t] = s_;
  }
  __syncthreads();
  if (t < 64) mu[t] = (ps[t] + ps[t + 64]) * (1.0f / DIM);
  __syncthreads();
  {
    int r = t & 63, ph = t >> 6;
    float m_ = mu[r], s_ = 0.f;
    #pragma unroll 8
    for (int k = ph * 96; k < ph * 96 + 96; ++k) {
      float d = As[k * 64 + (r ^ (4 * ((k >> 2) & 15)))] - m_;
      s_ += d * d;
    }
    ps[t] = s_;
  }
  __syncthreads();
  if (t < 64) inv[t] = rsqrtf((ps[t] + ps[t + 64]) * (1.0f / DIM) + 1e-5f);
  __syncthreads();
  for (int idx = t; idx < 64 * DIM; idx += 128) {
    int k = idx >> 6, r0 = idx & 63;
    int m = r0 ^ (4 * ((k >> 2) & 15));
    As[idx] = (As[idx] - mu[m]) * inv[m] * lnw[k] + lnb[k];
  }
  __syncthreads();
  int gm = t >> 3, gn = t & 7;      // 16 m-groups x 8 n-groups
  float acc[4][4];
  #pragma unroll
  for (int i = 0; i < 4; ++i)
    #pragma unroll
    for (int j = 0; j < 4; ++j) acc[i][j] = b[n0 + 4 * gn + j];
  #pragma unroll 4
  for (int kk = 0; kk < DIM; ++kk) {
    int mk = (kk >> 2) & 15, nk = (kk >> 2) & 7;
    float4 a = *(const float4*)&As[kk * 64 + 4 * (gm ^ mk)];
    float4 bv = *(const float4*)&Bs[kk * 32 + 4 * (gn ^ nk)];
    #pragma unroll
    for (int i = 0; i < 4; ++i) {
      float av = (i == 0) ? a.x : (i == 1) ? a.y : (i == 2) ? a.z : a.w;
      acc[i][0] += av * bv.x; acc[i][1] += av * bv.y;
      acc[i][2] += av * bv.z; acc[i][3] += av * bv.w;
    }
  }
  #pragma unroll
  for (int i = 0; i < 4; ++i)
    *(float4*)&out[(m0 + 4 * gm + i) * (2 * INNER) + n0 + 4 * gn] =
        make_float4(acc[i][0], acc[i][1], acc[i][2], acc[i][3]);
}

// 2) fused conv3x3+SiLU+qkv, block per token (576 x 384thr)
__global__ __launch_bounds__(384) void k_cqkv(const float* __restrict__ xin,
    const float* __restrict__ cw, const float* __restrict__ cb,
    const float* __restrict__ qw, const float* __restrict__ qb,
    const float* __restrict__ kw, const float* __restrict__ kb,
    const float* __restrict__ vw, const float* __restrict__ vb,
    float* __restrict__ xa, float* __restrict__ ginT) {
  int s = blockIdx.x, t = threadIdx.x;
  int h = s / WSZ, wc = s % WSZ;
  __shared__ float xat[INNER], xmt[INNER];
  float acc = cb[t];
  #pragma unroll
  for (int kh = 0; kh < 3; ++kh) {
    int hh = h + kh - 1;
    if (hh < 0 || hh >= HS) continue;
    #pragma unroll
    for (int kw2 = 0; kw2 < 3; ++kw2) {
      int ww = wc + kw2 - 1;
      if (ww < 0 || ww >= WSZ) continue;
      acc += xin[(hh * WSZ + ww) * (2 * INNER) + t] * cw[t * 9 + kh * 3 + kw2];
    }
  }
  float sil = acc / (1.0f + __expf(-acc));
  xat[t] = sil;
  xa[s * INNER + t] = sil;
  xmt[t] = xin[s * (2 * INNER) + t];
  __syncthreads();
  int n = t >> 2, o = t & 3;
  const float* xah = xat + n * 4;
  const float* xmh = xmt + n * 4;
  float q = qb[t], k = kb[t], v = vb[t];
  #pragma unroll
  for (int i = 0; i < 4; ++i) {
    float xq = xah[i], xm = xmh[i];
    q += xq * qw[n * 16 + o * 4 + i];
    k += xq * kw[n * 16 + o * 4 + i];
    v += xm * vw[n * 16 + o * 4 + i];
  }
  ginT[t * SEQ + s]               = q;
  ginT[(INNER + t) * SEQ + s]     = k;
  ginT[(2 * INNER + t) * SEQ + s] = v;
}

// 3) gate GEMM: C[192,576] = W[192,1152] @ ginT, K-split 4, single-shot stage.
//    grid (6,9,4), 128 thr, 4x4/thread. Ws[k][r^swz] swizzled.
#define GBK 288
__global__ __launch_bounds__(128) void k_gates(const float* __restrict__ ginT,
    const float* __restrict__ igw, const float* __restrict__ fgw,
    float* __restrict__ pig, float* __restrict__ pfg) {
  int bx = blockIdx.x, s0 = blockIdx.y * 64, ks = blockIdx.z;
  int k0 = ks * GBK;
  bool isig = bx < 3;
  int m0 = (isig ? bx : bx - 3) * 32;
  const float* wb = (isig ? igw : fgw) + m0 * GIN;
  __shared__ float Ws[GBK * 32];
  __shared__ float Gs[GBK * 64];
  int t = threadIdx.x;
  for (int idx = t; idx < 32 * 72; idx += 128) {
    int r = idx / 72, k4 = idx % 72;
    float4 v = *(const float4*)&wb[r * GIN + k0 + 4 * k4];
    int rw = r ^ (4 * (k4 & 7));
    Ws[(4 * k4 + 0) * 32 + rw] = v.x;
    Ws[(4 * k4 + 1) * 32 + rw] = v.y;
    Ws[(4 * k4 + 2) * 32 + rw] = v.z;
    Ws[(4 * k4 + 3) * 32 + rw] = v.w;
  }
  for (int idx = t; idx < GBK * 16; idx += 128) {
    int kk = idx / 16, s4 = idx % 16;
    *(float4*)&Gs[kk * 64 + 4 * s4] =
        *(const float4*)&ginT[(k0 + kk) * SEQ + s0 + 4 * s4];
  }
  __syncthreads();
  int gm = t >> 4, gn = t & 15;     // 8 m-groups x 16 n-groups
  float acc[4][4];
  #pragma unroll
  for (int i = 0; i < 4; ++i)
    #pragma unroll
    for (int j = 0; j < 4; ++j) acc[i][j] = 0.f;
  #pragma unroll 4
  for (int kk = 0; kk < GBK; ++kk) {
    int mk = (kk >> 2) & 7;
    float4 wv = *(const float4*)&Ws[kk * 32 + 4 * (gm ^ mk)];
    float4 gv = *(const float4*)&Gs[kk * 64 + 4 * gn];
    #pragma unroll
    for (int i = 0; i < 4; ++i) {
      float av = (i == 0) ? wv.x : (i == 1) ? wv.y : (i == 2) ? wv.z : wv.w;
      acc[i][0] += av * gv.x; acc[i][1] += av * gv.y;
      acc[i][2] += av * gv.z; acc[i][3] += av * gv.w;
    }
  }
  float* dstp = (isig ? pig : pfg) + ks * NHEAD * SEQ;
  #pragma unroll
  for (int i = 0; i < 4; ++i) {
    int mm = m0 + 4 * gm + i;
    *(float4*)&dstp[mm * SEQ + s0 + 4 * gn] =
        make_float4(acc[i][0], acc[i][1], acc[i][2], acc[i][3]);
  }
}

// 4) mLSTM: combine partials + log-sigmoid + block scans (sum & max) +
//    triangular accumulate (2 threads/row) + groupnorm.  grid (96,2), 576 thr.
__global__ __launch_bounds__(576) void k_mlstm(const float* __restrict__ ginT,
    const float* __restrict__ pig, const float* __restrict__ pfg,
    const float* __restrict__ igb, const float* __restrict__ fgb,
    const float* __restrict__ onw, float* __restrict__ hout) {
  int n = blockIdx.x, hh = blockIdx.y, t = threadIdx.x;
  int cnt2 = 288 * (hh + 1);
  __shared__ float ksm[SEQ * 4], vsm[SEQ * 4], esm[SEQ];
  __shared__ float bufA[SEQ], bufB[SEQ], bufC[SEQ];
  const int H4 = NHEAD * SEQ;
  float ai = 0.f;
  if (t < cnt2) {
    float a0 = ginT[(INNER + n * 4 + 0) * SEQ + t] * 0.5f;
    float a1 = ginT[(INNER + n * 4 + 1) * SEQ + t] * 0.5f;
    float a2 = ginT[(INNER + n * 4 + 2) * SEQ + t] * 0.5f;
    float a3 = ginT[(INNER + n * 4 + 3) * SEQ + t] * 0.5f;
    *(float4*)&ksm[t * 4] = make_float4(a0, a1, a2, a3);
    float b0 = ginT[(2 * INNER + n * 4 + 0) * SEQ + t];
    float b1 = ginT[(2 * INNER + n * 4 + 1) * SEQ + t];
    float b2 = ginT[(2 * INNER + n * 4 + 2) * SEQ + t];
    float b3 = ginT[(2 * INNER + n * 4 + 3) * SEQ + t];
    *(float4*)&vsm[t * 4] = make_float4(b0, b1, b2, b3);
    int off = n * SEQ + t;
    ai = igb[n] + pig[off] + pig[off + H4] + pig[off + 2 * H4] + pig[off + 3 * H4];
    float af = fgb[n] + pfg[off] + pfg[off + H4] + pfg[off + 2 * H4] + pfg[off + 3 * H4];
    float lf = (af >= 0.f) ? -log1pf(expf(-af)) : (af - log1pf(expf(af)));
    bufA[t] = lf;
  }
  __syncthreads();
  float* src = bufA; float* dst = bufB;
  for (int o2 = 1; o2 < cnt2; o2 <<= 1) {
    if (t < cnt2) {
      float v = src[t];
      if (t >= o2) v += src[t - o2];
      dst[t] = v;
    }
    __syncthreads();
    float* tmp = src; src = dst; dst = tmp;
  }
  if (t < cnt2) {
    float e = ai - src[t];
    esm[t] = e;
    dst[t] = e;
  }
  __syncthreads();
  float* srcM = dst; float* dstM = bufC;
  for (int o2 = 1; o2 < cnt2; o2 <<= 1) {
    if (t < cnt2) {
      float v = srcM[t];
      if (t >= o2) v = fmaxf(v, srcM[t - o2]);
      dstM[t] = v;
    }
    __syncthreads();
    float* tmp = srcM; srcM = dstM; dstM = tmp;
  }
  int r = (t < 288) ? t : t - 288;
  int half = (t >= 288) ? 1 : 0;
  int s = 288 * hh + r;
  float pm = srcM[s];
  float mxv = src[s] + pm;
  float q0 = ginT[(n * 4 + 0) * SEQ + s];
  float q1 = ginT[(n * 4 + 1) * SEQ + s];
  float q2 = ginT[(n * 4 + 2) * SEQ + s];
  float q3 = ginT[(n * 4 + 3) * SEQ + s];
  int N = s + 1, nA = (N + 1) >> 1;
  int lo = half ? nA : 0, hi = half ? N : nA;
  float csum = 0.f, h0 = 0.f, h1 = 0.f, h2 = 0.f, h3 = 0.f;
  for (int tt = lo; tt < hi; ++tt) {
    float d = __expf(esm[tt] - pm);
    float c = (q0 * ksm[tt*4] + q1 * ksm[tt*4+1] + q2 * ksm[tt*4+2] + q3 * ksm[tt*4+3]) * d;
    csum += c;
    h0 += c * vsm[tt*4]; h1 += c * vsm[tt*4+1]; h2 += c * vsm[tt*4+2]; h3 += c * vsm[tt*4+3];
  }
  __syncthreads();
  if (half) {
    ksm[r * 5 + 0] = csum; ksm[r * 5 + 1] = h0; ksm[r * 5 + 2] = h1;
    ksm[r * 5 + 3] = h2;   ksm[r * 5 + 4] = h3;
  }
  __syncthreads();
  if (!half) {
    csum += ksm[r * 5 + 0];
    h0 += ksm[r * 5 + 1]; h1 += ksm[r * 5 + 2];
    h2 += ksm[r * 5 + 3]; h3 += ksm[r * 5 + 4];
    float norm = fmaxf(fabsf(csum), __expf(-mxv)) + 1e-6f;
    float rr = 1.0f / norm;
    h0 *= rr; h1 *= rr; h2 *= rr; h3 *= rr;
    float mu = (h0 + h1 + h2 + h3) * 0.25f;
    float d0 = h0 - mu, d1 = h1 - mu, d2 = h2 - mu, d3 = h3 - mu;
    float var = (d0 * d0 + d1 * d1 + d2 * d2 + d3 * d3) * 0.25f;
    float inv = rsqrtf(var + 1e-5f);
    *(float4*)&hout[s * INNER + n * 4] = make_float4(
        d0 * inv * onw[n * 4 + 0], d1 * inv * onw[n * 4 + 1],
        d2 * inv * onw[n * 4 + 2], d3 * inv * onw[n * 4 + 3]);
  }
}

// 5) down GEMM + fused h2 epilogue. grid (36,6), 64 thr, 2m x 4n.
//    As row-major [16][388] (conflict-free stores, broadcast reads); Bs swizzled.
#define KPA 388
__global__ __launch_bounds__(64) void k_down(const float* __restrict__ hmat,
    const float* __restrict__ xa, const float* __restrict__ xin,
    const float* __restrict__ skip, const float* __restrict__ dw,
    const float* __restrict__ db, float* __restrict__ out) {
  int m0 = blockIdx.x * 16, n0 = blockIdx.y * 32;
  __shared__ float As[16 * KPA];
  __shared__ float Bs[INNER * 32];
  int t = threadIdx.x;
  for (int idx = t; idx < 16 * 96; idx += 64) {
    int r = idx / 96, k4 = idx % 96;
    int s = m0 + r;
    float4 zv = *(const float4*)&xin[s * (2 * INNER) + INNER + 4 * k4];
    float4 hm = *(const float4*)&hmat[s * INNER + 4 * k4];
    float4 xv = *(const float4*)&xa[s * INNER + 4 * k4];
    float4 sk = *(const float4*)&skip[4 * k4];
    float z, sil;
    float4 o;
    z = zv.x; sil = z / (1.0f + __expf(-z)); o.x = (hm.x + sk.x * xv.x) * sil;
    z = zv.y; sil = z / (1.0f + __expf(-z)); o.y = (hm.y + sk.y * xv.y) * sil;
    z = zv.z; sil = z / (1.0f + __expf(-z)); o.z = (hm.z + sk.z * xv.z) * sil;
    z = zv.w; sil = z / (1.0f + __expf(-z)); o.w = (hm.w + sk.w * xv.w) * sil;
    *(float4*)&As[r * KPA + 4 * k4] = o;
  }
  for (int idx = t; idx < 32 * 96; idx += 64) {
    int r = idx / 96, k4 = idx % 96;
    float4 v = *(const float4*)&dw[(n0 + r) * INNER + 4 * k4];
    int rw = r ^ (4 * (k4 & 7));
    Bs[(4 * k4 + 0) * 32 + rw] = v.x;
    Bs[(4 * k4 + 1) * 32 + rw] = v.y;
    Bs[(4 * k4 + 2) * 32 + rw] = v.z;
    Bs[(4 * k4 + 3) * 32 + rw] = v.w;
  }
  __syncthreads();
  int gm = t >> 3, gn = t & 7;      // 8 m-groups x 8 n-groups
  float acc[2][4];
  #pragma unroll
  for (int i = 0; i < 2; ++i)
    #pragma unroll
    for (int j = 0; j < 4; ++j) acc[i][j] = db[n0 + 4 * gn + j];
  #pragma unroll 4
  for (int kk = 0; kk < INNER; ++kk) {
    int nk = (kk >> 2) & 7;
    float a0 = As[(2 * gm) * KPA + kk];
    float a1 = As[(2 * gm + 1) * KPA + kk];
    float4 bv = *(const float4*)&Bs[kk * 32 + 4 * (gn ^ nk)];
    acc[0][0] += a0 * bv.x; acc[0][1] += a0 * bv.y;
    acc[0][2] += a0 * bv.z; acc[0][3] += a0 * bv.w;
    acc[1][0] += a1 * bv.x; acc[1][1] += a1 * bv.y;
    acc[1][2] += a1 * bv.z; acc[1][3] += a1 * bv.w;
  }
  #pragma unroll
  for (int i = 0; i < 2; ++i)
    *(float4*)&out[(m0 + 2 * gm + i) * DIM + n0 + 4 * gn] =
        make_float4(acc[i][0], acc[i][1], acc[i][2], acc[i][3]);
}

extern "C" void kernel_launch(void* const* d_in, const int* in_sizes, int n_in,
                              void* d_out, int out_size, void* d_ws, size_t ws_size,
                              hipStream_t stream) {
  const float* x      = (const float*)d_in[0];
  const float* ln_w   = (const float*)d_in[2];
  const float* ln_b   = (const float*)d_in[3];
  const float* up_w   = (const float*)d_in[4];
  const float* up_b   = (const float*)d_in[5];
  const float* q_w    = (const float*)d_in[8];
  const float* q_b    = (const float*)d_in[9];
  const float* k_w    = (const float*)d_in[10];
  const float* k_b    = (const float*)d_in[11];
  const float* v_w    = (const float*)d_in[12];
  const float* v_b    = (const float*)d_in[13];
  const float* conv_w = (const float*)d_in[14];
  const float* conv_b = (const float*)d_in[15];
  const float* ig_w   = (const float*)d_in[16];
  const float* ig_b   = (const float*)d_in[17];
  const float* fg_w   = (const float*)d_in[18];
  const float* fg_b   = (const float*)d_in[19];
  const float* onorm_w= (const float*)d_in[20];
  const float* skip   = (const float*)d_in[21];
  const float* down_w = (const float*)d_in[22];
  const float* down_b = (const float*)d_in[23];
  float* out = (float*)d_out;

  float* ws     = (float*)d_ws;
  float* xinner = ws;                       // 576*768
  float* xa     = xinner + SEQ * 2 * INNER; // 576*384
  float* ginT   = xa + SEQ * INNER;         // 1152*576
  float* pig    = ginT + GIN * SEQ;         // 4*96*576
  float* pfg    = pig + GKS * NHEAD * SEQ;  // 4*96*576
  float* hbuf   = pfg + GKS * NHEAD * SEQ;  // 576*384

  k_up   <<<dim3(9, 24), 128, 0, stream>>>(x, ln_w, ln_b, up_w, up_b, xinner);
  k_cqkv <<<SEQ, 384, 0, stream>>>(xinner, conv_w, conv_b,
                                   q_w, q_b, k_w, k_b, v_w, v_b, xa, ginT);
  k_gates<<<dim3(6, 9, GKS), 128, 0, stream>>>(ginT, ig_w, fg_w, pig, pfg);
  k_mlstm<<<dim3(NHEAD, 2), 576, 0, stream>>>(ginT, pig, pfg, ig_b, fg_b, onorm_w, hbuf);
  k_down <<<dim3(36, 6), 64, 0, stream>>>(hbuf, xa, xinner, skip, down_w, down_b, out);
}

// Round 10
// 103.884 us; speedup vs baseline: 1.3099x; 1.3099x over previous
//
#include <hip/hip_runtime.h>
#include <math.h>

#define SEQ 576
#define DIM 192
#define INNER 384
#define NHEAD 96
#define HS 24
#define WSZ 24
#define GIN 1152
#define GKS 4

// 1) fused LayerNorm + up-proj GEMM: x_inner = LN(x) @ up_w.T + up_b
//    grid (9,24): BM=64 x BN=32, 256 thr, 4m x 2n per thread (R8 config).
//    LDS: As[192][64] XOR-swizzled, Bs[192][32] XOR-swizzled (R9-verified).
__global__ __launch_bounds__(256) void k_up(const float* __restrict__ x,
    const float* __restrict__ lnw, const float* __restrict__ lnb,
    const float* __restrict__ w, const float* __restrict__ b,
    float* __restrict__ out) {
  int m0 = blockIdx.x * 64, n0 = blockIdx.y * 32;
  __shared__ float As[DIM * 64];
  __shared__ float Bs[DIM * 32];
  __shared__ float mu[64], inv[64], ps[192];
  int t = threadIdx.x;
  for (int idx = t; idx < 64 * 48; idx += 256) {
    int r = idx / 48, k4 = idx % 48;
    float4 v = *(const float4*)&x[(m0 + r) * DIM + 4 * k4];
    int rw = r ^ (4 * (k4 & 15));
    As[(4 * k4 + 0) * 64 + rw] = v.x;
    As[(4 * k4 + 1) * 64 + rw] = v.y;
    As[(4 * k4 + 2) * 64 + rw] = v.z;
    As[(4 * k4 + 3) * 64 + rw] = v.w;
  }
  for (int idx = t; idx < 32 * 48; idx += 256) {
    int r = idx / 48, k4 = idx % 48;
    float4 v = *(const float4*)&w[(n0 + r) * DIM + 4 * k4];
    int rw = r ^ (4 * (k4 & 7));
    Bs[(4 * k4 + 0) * 32 + rw] = v.x;
    Bs[(4 * k4 + 1) * 32 + rw] = v.y;
    Bs[(4 * k4 + 2) * 32 + rw] = v.z;
    Bs[(4 * k4 + 3) * 32 + rw] = v.w;
  }
  __syncthreads();
  if (t < 192) {
    int r = t % 64, ph = t / 64;
    float s_ = 0.f;
    #pragma unroll 8
    for (int k = ph * 64; k < ph * 64 + 64; ++k)
      s_ += As[k * 64 + (r ^ (4 * ((k >> 2) & 15)))];
    ps[t] = s_;
  }
  __syncthreads();
  if (t < 64) mu[t] = (ps[t] + ps[64 + t] + ps[128 + t]) * (1.0f / DIM);
  __syncthreads();
  if (t < 192) {
    int r = t % 64, ph = t / 64;
    float m_ = mu[r], s_ = 0.f;
    #pragma unroll 8
    for (int k = ph * 64; k < ph * 64 + 64; ++k) {
      float d = As[k * 64 + (r ^ (4 * ((k >> 2) & 15)))] - m_;
      s_ += d * d;
    }
    ps[t] = s_;
  }
  __syncthreads();
  if (t < 64) inv[t] = rsqrtf((ps[t] + ps[64 + t] + ps[128 + t]) * (1.0f / DIM) + 1e-5f);
  __syncthreads();
  for (int idx = t; idx < 64 * DIM; idx += 256) {
    int k = idx >> 6, r0 = idx & 63;
    int m = r0 ^ (4 * ((k >> 2) & 15));
    As[idx] = (As[idx] - mu[m]) * inv[m] * lnw[k] + lnb[k];
  }
  __syncthreads();
  int gm = t >> 4, gn = t & 15;     // 16 m-groups (4 rows) x 16 n-groups (2 outs)
  float acc[4][2];
  #pragma unroll
  for (int i = 0; i < 4; ++i)
    #pragma unroll
    for (int j = 0; j < 2; ++j) acc[i][j] = b[n0 + 2 * gn + j];
  #pragma unroll 4
  for (int kk = 0; kk < DIM; ++kk) {
    int mk = (kk >> 2) & 15, nk = 4 * ((kk >> 2) & 7);
    float4 a = *(const float4*)&As[kk * 64 + 4 * (gm ^ mk)];
    float2 bv = *(const float2*)&Bs[kk * 32 + ((2 * gn) ^ nk)];
    acc[0][0] += a.x * bv.x; acc[0][1] += a.x * bv.y;
    acc[1][0] += a.y * bv.x; acc[1][1] += a.y * bv.y;
    acc[2][0] += a.z * bv.x; acc[2][1] += a.z * bv.y;
    acc[3][0] += a.w * bv.x; acc[3][1] += a.w * bv.y;
  }
  #pragma unroll
  for (int i = 0; i < 4; ++i)
    *(float2*)&out[(m0 + 4 * gm + i) * (2 * INNER) + n0 + 2 * gn] =
        make_float2(acc[i][0], acc[i][1]);
}

// 2) fused conv3x3+SiLU+qkv, block per token (576 x 384thr)  [R8 verbatim]
__global__ __launch_bounds__(384) void k_cqkv(const float* __restrict__ xin,
    const float* __restrict__ cw, const float* __restrict__ cb,
    const float* __restrict__ qw, const float* __restrict__ qb,
    const float* __restrict__ kw, const float* __restrict__ kb,
    const float* __restrict__ vw, const float* __restrict__ vb,
    float* __restrict__ xa, float* __restrict__ ginT) {
  int s = blockIdx.x, t = threadIdx.x;
  int h = s / WSZ, wc = s % WSZ;
  __shared__ float xat[INNER], xmt[INNER];
  float acc = cb[t];
  #pragma unroll
  for (int kh = 0; kh < 3; ++kh) {
    int hh = h + kh - 1;
    if (hh < 0 || hh >= HS) continue;
    #pragma unroll
    for (int kw2 = 0; kw2 < 3; ++kw2) {
      int ww = wc + kw2 - 1;
      if (ww < 0 || ww >= WSZ) continue;
      acc += xin[(hh * WSZ + ww) * (2 * INNER) + t] * cw[t * 9 + kh * 3 + kw2];
    }
  }
  float sil = acc / (1.0f + __expf(-acc));
  xat[t] = sil;
  xa[s * INNER + t] = sil;
  xmt[t] = xin[s * (2 * INNER) + t];
  __syncthreads();
  int n = t >> 2, o = t & 3;
  const float* xah = xat + n * 4;
  const float* xmh = xmt + n * 4;
  float q = qb[t], k = kb[t], v = vb[t];
  #pragma unroll
  for (int i = 0; i < 4; ++i) {
    float xq = xah[i], xm = xmh[i];
    q += xq * qw[n * 16 + o * 4 + i];
    k += xq * kw[n * 16 + o * 4 + i];
    v += xm * vw[n * 16 + o * 4 + i];
  }
  ginT[t * SEQ + s]               = q;
  ginT[(INNER + t) * SEQ + s]     = k;
  ginT[(2 * INNER + t) * SEQ + s] = v;
}

// 3) gate GEMM: C[192,576] = W[192,1152] @ ginT, K-split 4, single-shot stage.
//    grid (6,9,4), 256 thr, 2m x 4n per thread (R8 config).
//    Ws[288][32] XOR-swizzled; Gs[288][64] linear (already conflict-free).
#define GBK 288
__global__ __launch_bounds__(256) void k_gates(const float* __restrict__ ginT,
    const float* __restrict__ igw, const float* __restrict__ fgw,
    float* __restrict__ pig, float* __restrict__ pfg) {
  int bx = blockIdx.x, s0 = blockIdx.y * 64, ks = blockIdx.z;
  int k0 = ks * GBK;
  bool isig = bx < 3;
  int m0 = (isig ? bx : bx - 3) * 32;
  const float* wb = (isig ? igw : fgw) + m0 * GIN;
  __shared__ float Ws[GBK * 32];
  __shared__ float Gs[GBK * 64];
  int t = threadIdx.x;
  for (int idx = t; idx < 32 * 72; idx += 256) {
    int r = idx / 72, k4 = idx % 72;
    float4 v = *(const float4*)&wb[r * GIN + k0 + 4 * k4];
    int rw = r ^ (4 * (k4 & 7));
    Ws[(4 * k4 + 0) * 32 + rw] = v.x;
    Ws[(4 * k4 + 1) * 32 + rw] = v.y;
    Ws[(4 * k4 + 2) * 32 + rw] = v.z;
    Ws[(4 * k4 + 3) * 32 + rw] = v.w;
  }
  for (int idx = t; idx < GBK * 16; idx += 256) {
    int kk = idx / 16, s4 = idx % 16;
    *(float4*)&Gs[kk * 64 + 4 * s4] =
        *(const float4*)&ginT[(k0 + kk) * SEQ + s0 + 4 * s4];
  }
  __syncthreads();
  int gm = t >> 4, gn = t & 15;
  float acc[2][4] = {{0.f,0.f,0.f,0.f},{0.f,0.f,0.f,0.f}};
  #pragma unroll 4
  for (int kk = 0; kk < GBK; ++kk) {
    int nk = 4 * ((kk >> 2) & 7);
    float2 wv = *(const float2*)&Ws[kk * 32 + ((2 * gm) ^ nk)];
    float4 gv = *(const float4*)&Gs[kk * 64 + 4 * gn];
    acc[0][0] += wv.x * gv.x; acc[0][1] += wv.x * gv.y;
    acc[0][2] += wv.x * gv.z; acc[0][3] += wv.x * gv.w;
    acc[1][0] += wv.y * gv.x; acc[1][1] += wv.y * gv.y;
    acc[1][2] += wv.y * gv.z; acc[1][3] += wv.y * gv.w;
  }
  float* dstp = (isig ? pig : pfg) + ks * NHEAD * SEQ;
  #pragma unroll
  for (int i = 0; i < 2; ++i) {
    int mm = m0 + 2 * gm + i;
    *(float4*)&dstp[mm * SEQ + s0 + 4 * gn] =
        make_float4(acc[i][0], acc[i][1], acc[i][2], acc[i][3]);
  }
}

// 4) mLSTM: combine partials + log-sigmoid + block scans + triangular
//    accumulate (2 threads/row) + groupnorm.  grid (96,2), 576 thr. [R8 verbatim]
__global__ __launch_bounds__(576) void k_mlstm(const float* __restrict__ ginT,
    const float* __restrict__ pig, const float* __restrict__ pfg,
    const float* __restrict__ igb, const float* __restrict__ fgb,
    const float* __restrict__ onw, float* __restrict__ hout) {
  int n = blockIdx.x, hh = blockIdx.y, t = threadIdx.x;
  int cnt2 = 288 * (hh + 1);
  __shared__ float ksm[SEQ * 4], vsm[SEQ * 4], esm[SEQ];
  __shared__ float bufA[SEQ], bufB[SEQ], bufC[SEQ];
  const int H4 = NHEAD * SEQ;
  float ai = 0.f;
  if (t < cnt2) {
    float a0 = ginT[(INNER + n * 4 + 0) * SEQ + t] * 0.5f;
    float a1 = ginT[(INNER + n * 4 + 1) * SEQ + t] * 0.5f;
    float a2 = ginT[(INNER + n * 4 + 2) * SEQ + t] * 0.5f;
    float a3 = ginT[(INNER + n * 4 + 3) * SEQ + t] * 0.5f;
    *(float4*)&ksm[t * 4] = make_float4(a0, a1, a2, a3);
    float b0 = ginT[(2 * INNER + n * 4 + 0) * SEQ + t];
    float b1 = ginT[(2 * INNER + n * 4 + 1) * SEQ + t];
    float b2 = ginT[(2 * INNER + n * 4 + 2) * SEQ + t];
    float b3 = ginT[(2 * INNER + n * 4 + 3) * SEQ + t];
    *(float4*)&vsm[t * 4] = make_float4(b0, b1, b2, b3);
    int off = n * SEQ + t;
    ai = igb[n] + pig[off] + pig[off + H4] + pig[off + 2 * H4] + pig[off + 3 * H4];
    float af = fgb[n] + pfg[off] + pfg[off + H4] + pfg[off + 2 * H4] + pfg[off + 3 * H4];
    float lf = (af >= 0.f) ? -log1pf(expf(-af)) : (af - log1pf(expf(af)));
    bufA[t] = lf;
  }
  __syncthreads();
  float* src = bufA; float* dst = bufB;
  for (int o2 = 1; o2 < cnt2; o2 <<= 1) {
    if (t < cnt2) {
      float v = src[t];
      if (t >= o2) v += src[t - o2];
      dst[t] = v;
    }
    __syncthreads();
    float* tmp = src; src = dst; dst = tmp;
  }
  if (t < cnt2) {
    float e = ai - src[t];
    esm[t] = e;
    dst[t] = e;
  }
  __syncthreads();
  float* srcM = dst; float* dstM = bufC;
  for (int o2 = 1; o2 < cnt2; o2 <<= 1) {
    if (t < cnt2) {
      float v = srcM[t];
      if (t >= o2) v = fmaxf(v, srcM[t - o2]);
      dstM[t] = v;
    }
    __syncthreads();
    float* tmp = srcM; srcM = dstM; dstM = tmp;
  }
  int r = (t < 288) ? t : t - 288;
  int half = (t >= 288) ? 1 : 0;
  int s = 288 * hh + r;
  float pm = srcM[s];
  float mxv = src[s] + pm;
  float q0 = ginT[(n * 4 + 0) * SEQ + s];
  float q1 = ginT[(n * 4 + 1) * SEQ + s];
  float q2 = ginT[(n * 4 + 2) * SEQ + s];
  float q3 = ginT[(n * 4 + 3) * SEQ + s];
  int N = s + 1, nA = (N + 1) >> 1;
  int lo = half ? nA : 0, hi = half ? N : nA;
  float csum = 0.f, h0 = 0.f, h1 = 0.f, h2 = 0.f, h3 = 0.f;
  for (int tt = lo; tt < hi; ++tt) {
    float d = __expf(esm[tt] - pm);
    float c = (q0 * ksm[tt*4] + q1 * ksm[tt*4+1] + q2 * ksm[tt*4+2] + q3 * ksm[tt*4+3]) * d;
    csum += c;
    h0 += c * vsm[tt*4]; h1 += c * vsm[tt*4+1]; h2 += c * vsm[tt*4+2]; h3 += c * vsm[tt*4+3];
  }
  __syncthreads();
  if (half) {
    ksm[r * 5 + 0] = csum; ksm[r * 5 + 1] = h0; ksm[r * 5 + 2] = h1;
    ksm[r * 5 + 3] = h2;   ksm[r * 5 + 4] = h3;
  }
  __syncthreads();
  if (!half) {
    csum += ksm[r * 5 + 0];
    h0 += ksm[r * 5 + 1]; h1 += ksm[r * 5 + 2];
    h2 += ksm[r * 5 + 3]; h3 += ksm[r * 5 + 4];
    float norm = fmaxf(fabsf(csum), __expf(-mxv)) + 1e-6f;
    float rr = 1.0f / norm;
    h0 *= rr; h1 *= rr; h2 *= rr; h3 *= rr;
    float mu = (h0 + h1 + h2 + h3) * 0.25f;
    float d0 = h0 - mu, d1 = h1 - mu, d2 = h2 - mu, d3 = h3 - mu;
    float var = (d0 * d0 + d1 * d1 + d2 * d2 + d3 * d3) * 0.25f;
    float inv = rsqrtf(var + 1e-5f);
    *(float4*)&hout[s * INNER + n * 4] = make_float4(
        d0 * inv * onw[n * 4 + 0], d1 * inv * onw[n * 4 + 1],
        d2 * inv * onw[n * 4 + 2], d3 * inv * onw[n * 4 + 3]);
  }
}

// 5) down GEMM + fused h2 epilogue. grid (36,6), 128 thr, 2m x 2n (R8 config).
//    As row-major [16][388] (conflict-free both sides); Bs[384][32] XOR-swizzled.
#define KPA 388
__global__ __launch_bounds__(128) void k_down(const float* __restrict__ hmat,
    const float* __restrict__ xa, const float* __restrict__ xin,
    const float* __restrict__ skip, const float* __restrict__ dw,
    const float* __restrict__ db, float* __restrict__ out) {
  int m0 = blockIdx.x * 16, n0 = blockIdx.y * 32;
  __shared__ float As[16 * KPA];
  __shared__ float Bs[INNER * 32];
  int t = threadIdx.x;
  for (int idx = t; idx < 16 * 96; idx += 128) {
    int r = idx / 96, k4 = idx % 96;
    int s = m0 + r;
    float4 zv = *(const float4*)&xin[s * (2 * INNER) + INNER + 4 * k4];
    float4 hm = *(const float4*)&hmat[s * INNER + 4 * k4];
    float4 xv = *(const float4*)&xa[s * INNER + 4 * k4];
    float4 sk = *(const float4*)&skip[4 * k4];
    float z, sil;
    float4 o;
    z = zv.x; sil = z / (1.0f + __expf(-z)); o.x = (hm.x + sk.x * xv.x) * sil;
    z = zv.y; sil = z / (1.0f + __expf(-z)); o.y = (hm.y + sk.y * xv.y) * sil;
    z = zv.z; sil = z / (1.0f + __expf(-z)); o.z = (hm.z + sk.z * xv.z) * sil;
    z = zv.w; sil = z / (1.0f + __expf(-z)); o.w = (hm.w + sk.w * xv.w) * sil;
    *(float4*)&As[r * KPA + 4 * k4] = o;
  }
  for (int idx = t; idx < 32 * 96; idx += 128) {
    int r = idx / 96, k4 = idx % 96;
    float4 v = *(const float4*)&dw[(n0 + r) * INNER + 4 * k4];
    int rw = r ^ (4 * (k4 & 7));
    Bs[(4 * k4 + 0) * 32 + rw] = v.x;
    Bs[(4 * k4 + 1) * 32 + rw] = v.y;
    Bs[(4 * k4 + 2) * 32 + rw] = v.z;
    Bs[(4 * k4 + 3) * 32 + rw] = v.w;
  }
  __syncthreads();
  int gm = t >> 4, gn = t & 15;     // 8 m-groups (2 rows) x 16 n-groups (2 outs)
  float acc[2][2];
  #pragma unroll
  for (int i = 0; i < 2; ++i)
    #pragma unroll
    for (int j = 0; j < 2; ++j) acc[i][j] = db[n0 + 2 * gn + j];
  #pragma unroll 4
  for (int kk = 0; kk < INNER; ++kk) {
    int nk = 4 * ((kk >> 2) & 7);
    float a0 = As[(2 * gm) * KPA + kk];
    float a1 = As[(2 * gm + 1) * KPA + kk];
    float2 bv = *(const float2*)&Bs[kk * 32 + ((2 * gn) ^ nk)];
    acc[0][0] += a0 * bv.x; acc[0][1] += a0 * bv.y;
    acc[1][0] += a1 * bv.x; acc[1][1] += a1 * bv.y;
  }
  #pragma unroll
  for (int i = 0; i < 2; ++i)
    *(float2*)&out[(m0 + 2 * gm + i) * DIM + n0 + 2 * gn] =
        make_float2(acc[i][0], acc[i][1]);
}

extern "C" void kernel_launch(void* const* d_in, const int* in_sizes, int n_in,
                              void* d_out, int out_size, void* d_ws, size_t ws_size,
                              hipStream_t stream) {
  const float* x      = (const float*)d_in[0];
  const float* ln_w   = (const float*)d_in[2];
  const float* ln_b   = (const float*)d_in[3];
  const float* up_w   = (const float*)d_in[4];
  const float* up_b   = (const float*)d_in[5];
  const float* q_w    = (const float*)d_in[8];
  const float* q_b    = (const float*)d_in[9];
  const float* k_w    = (const float*)d_in[10];
  const float* k_b    = (const float*)d_in[11];
  const float* v_w    = (const float*)d_in[12];
  const float* v_b    = (const float*)d_in[13];
  const float* conv_w = (const float*)d_in[14];
  const float* conv_b = (const float*)d_in[15];
  const float* ig_w   = (const float*)d_in[16];
  const float* ig_b   = (const float*)d_in[17];
  const float* fg_w   = (const float*)d_in[18];
  const float* fg_b   = (const float*)d_in[19];
  const float* onorm_w= (const float*)d_in[20];
  const float* skip   = (const float*)d_in[21];
  const float* down_w = (const float*)d_in[22];
  const float* down_b = (const float*)d_in[23];
  float* out = (float*)d_out;

  float* ws     = (float*)d_ws;
  float* xinner = ws;                       // 576*768
  float* xa     = xinner + SEQ * 2 * INNER; // 576*384
  float* ginT   = xa + SEQ * INNER;         // 1152*576
  float* pig    = ginT + GIN * SEQ;         // 4*96*576
  float* pfg    = pig + GKS * NHEAD * SEQ;  // 4*96*576
  float* hbuf   = pfg + GKS * NHEAD * SEQ;  // 576*384

  k_up   <<<dim3(9, 24), 256, 0, stream>>>(x, ln_w, ln_b, up_w, up_b, xinner);
  k_cqkv <<<SEQ, 384, 0, stream>>>(xinner, conv_w, conv_b,
                                   q_w, q_b, k_w, k_b, v_w, v_b, xa, ginT);
  k_gates<<<dim3(6, 9, GKS), 256, 0, stream>>>(ginT, ig_w, fg_w, pig, pfg);
  k_mlstm<<<dim3(NHEAD, 2), 576, 0, stream>>>(ginT, pig, pfg, ig_b, fg_b, onorm_w, hbuf);
  k_down <<<dim3(36, 6), 128, 0, stream>>>(hbuf, xa, xinner, skip, down_w, down_b, out);
}

// Round 11
// 101.481 us; speedup vs baseline: 1.3409x; 1.0237x over previous
//
#include <hip/hip_runtime.h>
#include <math.h>

#define SEQ 576
#define DIM 192
#define INNER 384
#define NHEAD 96
#define HS 24
#define WSZ 24
#define GIN 1152
#define GKS 4

// 1) fused LayerNorm + up-proj GEMM  [R10 verbatim]
__global__ __launch_bounds__(256) void k_up(const float* __restrict__ x,
    const float* __restrict__ lnw, const float* __restrict__ lnb,
    const float* __restrict__ w, const float* __restrict__ b,
    float* __restrict__ out) {
  int m0 = blockIdx.x * 64, n0 = blockIdx.y * 32;
  __shared__ float As[DIM * 64];
  __shared__ float Bs[DIM * 32];
  __shared__ float mu[64], inv[64], ps[192];
  int t = threadIdx.x;
  for (int idx = t; idx < 64 * 48; idx += 256) {
    int r = idx / 48, k4 = idx % 48;
    float4 v = *(const float4*)&x[(m0 + r) * DIM + 4 * k4];
    int rw = r ^ (4 * (k4 & 15));
    As[(4 * k4 + 0) * 64 + rw] = v.x;
    As[(4 * k4 + 1) * 64 + rw] = v.y;
    As[(4 * k4 + 2) * 64 + rw] = v.z;
    As[(4 * k4 + 3) * 64 + rw] = v.w;
  }
  for (int idx = t; idx < 32 * 48; idx += 256) {
    int r = idx / 48, k4 = idx % 48;
    float4 v = *(const float4*)&w[(n0 + r) * DIM + 4 * k4];
    int rw = r ^ (4 * (k4 & 7));
    Bs[(4 * k4 + 0) * 32 + rw] = v.x;
    Bs[(4 * k4 + 1) * 32 + rw] = v.y;
    Bs[(4 * k4 + 2) * 32 + rw] = v.z;
    Bs[(4 * k4 + 3) * 32 + rw] = v.w;
  }
  __syncthreads();
  if (t < 192) {
    int r = t % 64, ph = t / 64;
    float s_ = 0.f;
    #pragma unroll 8
    for (int k = ph * 64; k < ph * 64 + 64; ++k)
      s_ += As[k * 64 + (r ^ (4 * ((k >> 2) & 15)))];
    ps[t] = s_;
  }
  __syncthreads();
  if (t < 64) mu[t] = (ps[t] + ps[64 + t] + ps[128 + t]) * (1.0f / DIM);
  __syncthreads();
  if (t < 192) {
    int r = t % 64, ph = t / 64;
    float m_ = mu[r], s_ = 0.f;
    #pragma unroll 8
    for (int k = ph * 64; k < ph * 64 + 64; ++k) {
      float d = As[k * 64 + (r ^ (4 * ((k >> 2) & 15)))] - m_;
      s_ += d * d;
    }
    ps[t] = s_;
  }
  __syncthreads();
  if (t < 64) inv[t] = rsqrtf((ps[t] + ps[64 + t] + ps[128 + t]) * (1.0f / DIM) + 1e-5f);
  __syncthreads();
  for (int idx = t; idx < 64 * DIM; idx += 256) {
    int k = idx >> 6, r0 = idx & 63;
    int m = r0 ^ (4 * ((k >> 2) & 15));
    As[idx] = (As[idx] - mu[m]) * inv[m] * lnw[k] + lnb[k];
  }
  __syncthreads();
  int gm = t >> 4, gn = t & 15;
  float acc[4][2];
  #pragma unroll
  for (int i = 0; i < 4; ++i)
    #pragma unroll
    for (int j = 0; j < 2; ++j) acc[i][j] = b[n0 + 2 * gn + j];
  #pragma unroll 4
  for (int kk = 0; kk < DIM; ++kk) {
    int mk = (kk >> 2) & 15, nk = 4 * ((kk >> 2) & 7);
    float4 a = *(const float4*)&As[kk * 64 + 4 * (gm ^ mk)];
    float2 bv = *(const float2*)&Bs[kk * 32 + ((2 * gn) ^ nk)];
    acc[0][0] += a.x * bv.x; acc[0][1] += a.x * bv.y;
    acc[1][0] += a.y * bv.x; acc[1][1] += a.y * bv.y;
    acc[2][0] += a.z * bv.x; acc[2][1] += a.z * bv.y;
    acc[3][0] += a.w * bv.x; acc[3][1] += a.w * bv.y;
  }
  #pragma unroll
  for (int i = 0; i < 4; ++i)
    *(float2*)&out[(m0 + 4 * gm + i) * (2 * INNER) + n0 + 2 * gn] =
        make_float2(acc[i][0], acc[i][1]);
}

// 2) fused conv3x3+SiLU+qkv  [R10 verbatim]
__global__ __launch_bounds__(384) void k_cqkv(const float* __restrict__ xin,
    const float* __restrict__ cw, const float* __restrict__ cb,
    const float* __restrict__ qw, const float* __restrict__ qb,
    const float* __restrict__ kw, const float* __restrict__ kb,
    const float* __restrict__ vw, const float* __restrict__ vb,
    float* __restrict__ xa, float* __restrict__ ginT) {
  int s = blockIdx.x, t = threadIdx.x;
  int h = s / WSZ, wc = s % WSZ;
  __shared__ float xat[INNER], xmt[INNER];
  float acc = cb[t];
  #pragma unroll
  for (int kh = 0; kh < 3; ++kh) {
    int hh = h + kh - 1;
    if (hh < 0 || hh >= HS) continue;
    #pragma unroll
    for (int kw2 = 0; kw2 < 3; ++kw2) {
      int ww = wc + kw2 - 1;
      if (ww < 0 || ww >= WSZ) continue;
      acc += xin[(hh * WSZ + ww) * (2 * INNER) + t] * cw[t * 9 + kh * 3 + kw2];
    }
  }
  float sil = acc / (1.0f + __expf(-acc));
  xat[t] = sil;
  xa[s * INNER + t] = sil;
  xmt[t] = xin[s * (2 * INNER) + t];
  __syncthreads();
  int n = t >> 2, o = t & 3;
  const float* xah = xat + n * 4;
  const float* xmh = xmt + n * 4;
  float q = qb[t], k = kb[t], v = vb[t];
  #pragma unroll
  for (int i = 0; i < 4; ++i) {
    float xq = xah[i], xm = xmh[i];
    q += xq * qw[n * 16 + o * 4 + i];
    k += xq * kw[n * 16 + o * 4 + i];
    v += xm * vw[n * 16 + o * 4 + i];
  }
  ginT[t * SEQ + s]               = q;
  ginT[(INNER + t) * SEQ + s]     = k;
  ginT[(2 * INNER + t) * SEQ + s] = v;
}

// 3) gate GEMM  [R10 verbatim]
#define GBK 288
__global__ __launch_bounds__(256) void k_gates(const float* __restrict__ ginT,
    const float* __restrict__ igw, const float* __restrict__ fgw,
    float* __restrict__ pig, float* __restrict__ pfg) {
  int bx = blockIdx.x, s0 = blockIdx.y * 64, ks = blockIdx.z;
  int k0 = ks * GBK;
  bool isig = bx < 3;
  int m0 = (isig ? bx : bx - 3) * 32;
  const float* wb = (isig ? igw : fgw) + m0 * GIN;
  __shared__ float Ws[GBK * 32];
  __shared__ float Gs[GBK * 64];
  int t = threadIdx.x;
  for (int idx = t; idx < 32 * 72; idx += 256) {
    int r = idx / 72, k4 = idx % 72;
    float4 v = *(const float4*)&wb[r * GIN + k0 + 4 * k4];
    int rw = r ^ (4 * (k4 & 7));
    Ws[(4 * k4 + 0) * 32 + rw] = v.x;
    Ws[(4 * k4 + 1) * 32 + rw] = v.y;
    Ws[(4 * k4 + 2) * 32 + rw] = v.z;
    Ws[(4 * k4 + 3) * 32 + rw] = v.w;
  }
  for (int idx = t; idx < GBK * 16; idx += 256) {
    int kk = idx / 16, s4 = idx % 16;
    *(float4*)&Gs[kk * 64 + 4 * s4] =
        *(const float4*)&ginT[(k0 + kk) * SEQ + s0 + 4 * s4];
  }
  __syncthreads();
  int gm = t >> 4, gn = t & 15;
  float acc[2][4] = {{0.f,0.f,0.f,0.f},{0.f,0.f,0.f,0.f}};
  #pragma unroll 4
  for (int kk = 0; kk < GBK; ++kk) {
    int nk = 4 * ((kk >> 2) & 7);
    float2 wv = *(const float2*)&Ws[kk * 32 + ((2 * gm) ^ nk)];
    float4 gv = *(const float4*)&Gs[kk * 64 + 4 * gn];
    acc[0][0] += wv.x * gv.x; acc[0][1] += wv.x * gv.y;
    acc[0][2] += wv.x * gv.z; acc[0][3] += wv.x * gv.w;
    acc[1][0] += wv.y * gv.x; acc[1][1] += wv.y * gv.y;
    acc[1][2] += wv.y * gv.z; acc[1][3] += wv.y * gv.w;
  }
  float* dstp = (isig ? pig : pfg) + ks * NHEAD * SEQ;
  #pragma unroll
  for (int i = 0; i < 2; ++i) {
    int mm = m0 + 2 * gm + i;
    *(float4*)&dstp[mm * SEQ + s0 + 4 * gn] =
        make_float4(acc[i][0], acc[i][1], acc[i][2], acc[i][3]);
  }
}

// 4) mLSTM v2: shuffle scans + 4-row register blocking x 8-col split +
//    shuffle partial reduce.  grid (96,2), 576 thr.
__global__ __launch_bounds__(576) void k_mlstm(const float* __restrict__ ginT,
    const float* __restrict__ pig, const float* __restrict__ pfg,
    const float* __restrict__ igb, const float* __restrict__ fgb,
    const float* __restrict__ onw, float* __restrict__ hout) {
  int n = blockIdx.x, hh = blockIdx.y, t = threadIdx.x;
  int base = 288 * hh;
  int cnt2 = base + 288;            // scans cover [0, cnt2)
  __shared__ float ksm[SEQ * 4], vsm[SEQ * 4], esm[SEQ];
  __shared__ float qsm[288 * 4];
  __shared__ float lfcs[SEQ], pms[SEQ];
  __shared__ float wsum[16], wmax[16];
  const int H4 = NHEAD * SEQ;
  int lane = t & 63, w = t >> 6;
  float ai = 0.f, lf = 0.f;
  if (t < cnt2) {
    float a0 = ginT[(INNER + n * 4 + 0) * SEQ + t] * 0.5f;
    float a1 = ginT[(INNER + n * 4 + 1) * SEQ + t] * 0.5f;
    float a2 = ginT[(INNER + n * 4 + 2) * SEQ + t] * 0.5f;
    float a3 = ginT[(INNER + n * 4 + 3) * SEQ + t] * 0.5f;
    *(float4*)&ksm[t * 4] = make_float4(a0, a1, a2, a3);
    float b0 = ginT[(2 * INNER + n * 4 + 0) * SEQ + t];
    float b1 = ginT[(2 * INNER + n * 4 + 1) * SEQ + t];
    float b2 = ginT[(2 * INNER + n * 4 + 2) * SEQ + t];
    float b3 = ginT[(2 * INNER + n * 4 + 3) * SEQ + t];
    *(float4*)&vsm[t * 4] = make_float4(b0, b1, b2, b3);
    if (t >= base) {
      int r = t - base;
      qsm[r * 4 + 0] = ginT[(n * 4 + 0) * SEQ + t];
      qsm[r * 4 + 1] = ginT[(n * 4 + 1) * SEQ + t];
      qsm[r * 4 + 2] = ginT[(n * 4 + 2) * SEQ + t];
      qsm[r * 4 + 3] = ginT[(n * 4 + 3) * SEQ + t];
    }
    int off = n * SEQ + t;
    ai = igb[n] + pig[off] + pig[off + H4] + pig[off + 2 * H4] + pig[off + 3 * H4];
    float af = fgb[n] + pfg[off] + pfg[off + H4] + pfg[off + 2 * H4] + pfg[off + 3 * H4];
    lf = (af >= 0.f) ? -log1pf(expf(-af)) : (af - log1pf(expf(af)));
  }
  // --- inclusive sum scan of lf (wave shuffle + cross-wave carry) ---
  float v = (t < cnt2) ? lf : 0.f;
  #pragma unroll
  for (int o2 = 1; o2 < 64; o2 <<= 1) {
    float u = __shfl_up(v, o2);
    if (lane >= o2) v += u;
  }
  if (lane == 63) wsum[w] = v;
  __syncthreads();
  if (t < 16) {
    float sv = (t < 9) ? wsum[t] : 0.f;
    #pragma unroll
    for (int o2 = 1; o2 < 16; o2 <<= 1) {
      float u = __shfl_up(sv, o2);
      if (t >= o2) sv += u;
    }
    wsum[t] = sv;
  }
  __syncthreads();
  float lfc = v + ((w > 0) ? wsum[w - 1] : 0.f);
  float e = ai - lfc;
  // --- inclusive max scan of e ---
  float m = (t < cnt2) ? e : -3.0e38f;
  #pragma unroll
  for (int o2 = 1; o2 < 64; o2 <<= 1) {
    float u = __shfl_up(m, o2);
    if (lane >= o2) m = fmaxf(m, u);
  }
  if (lane == 63) wmax[w] = m;
  __syncthreads();
  if (t < 16) {
    float sv = (t < 9) ? wmax[t] : -3.0e38f;
    #pragma unroll
    for (int o2 = 1; o2 < 16; o2 <<= 1) {
      float u = __shfl_up(sv, o2);
      if (t >= o2) sv = fmaxf(sv, u);
    }
    wmax[t] = sv;
  }
  __syncthreads();
  float pm = (w > 0) ? fmaxf(m, wmax[w - 1]) : m;
  if (t < cnt2) {
    esm[t] = e;
    lfcs[t] = lfc;
    pms[t] = pm;
  }
  __syncthreads();
  // --- triangular accumulate: thread (rq, cq), rows s0..s0+3, col-chunk cq/8 ---
  int rq = t >> 3, cq = t & 7;      // rq 0..71
  int s0 = base + 4 * rq;
  int N = s0 + 4;
  float pmv[4], qv[4][4];
  #pragma unroll
  for (int i = 0; i < 4; ++i) {
    pmv[i] = pms[s0 + i];
    *(float4*)&qv[i][0] = *(float4*)&qsm[(4 * rq + i) * 4];
  }
  int ch = (N + 7) >> 3;
  int lo = cq * ch, hi = min(lo + ch, N);
  float cs[4] = {0.f, 0.f, 0.f, 0.f};
  float hv[4][4];
  #pragma unroll
  for (int i = 0; i < 4; ++i)
    #pragma unroll
    for (int j = 0; j < 4; ++j) hv[i][j] = 0.f;
  for (int tt = lo; tt < hi; ++tt) {
    float e3 = esm[tt];
    float4 kv = *(const float4*)&ksm[tt * 4];
    float4 vv = *(const float4*)&vsm[tt * 4];
    #pragma unroll
    for (int i = 0; i < 4; ++i) {
      if (tt <= s0 + i) {
        float d = __expf(e3 - pmv[i]);
        float c = (qv[i][0] * kv.x + qv[i][1] * kv.y +
                   qv[i][2] * kv.z + qv[i][3] * kv.w) * d;
        cs[i] += c;
        hv[i][0] += c * vv.x; hv[i][1] += c * vv.y;
        hv[i][2] += c * vv.z; hv[i][3] += c * vv.w;
      }
    }
  }
  // --- reduce across the 8 col-splits (8 consecutive lanes) ---
  #pragma unroll
  for (int o2 = 4; o2 > 0; o2 >>= 1) {
    #pragma unroll
    for (int i = 0; i < 4; ++i) {
      cs[i] += __shfl_down(cs[i], o2);
      hv[i][0] += __shfl_down(hv[i][0], o2);
      hv[i][1] += __shfl_down(hv[i][1], o2);
      hv[i][2] += __shfl_down(hv[i][2], o2);
      hv[i][3] += __shfl_down(hv[i][3], o2);
    }
  }
  if (cq == 0) {
    #pragma unroll
    for (int i = 0; i < 4; ++i) {
      int s = s0 + i;
      float mxv = lfcs[s] + pmv[i];
      float norm = fmaxf(fabsf(cs[i]), __expf(-mxv)) + 1e-6f;
      float rr = 1.0f / norm;
      float h0 = hv[i][0] * rr, h1 = hv[i][1] * rr;
      float h2 = hv[i][2] * rr, h3 = hv[i][3] * rr;
      float mu = (h0 + h1 + h2 + h3) * 0.25f;
      float d0 = h0 - mu, d1 = h1 - mu, d2 = h2 - mu, d3 = h3 - mu;
      float var = (d0 * d0 + d1 * d1 + d2 * d2 + d3 * d3) * 0.25f;
      float inv = rsqrtf(var + 1e-5f);
      *(float4*)&hout[s * INNER + n * 4] = make_float4(
          d0 * inv * onw[n * 4 + 0], d1 * inv * onw[n * 4 + 1],
          d2 * inv * onw[n * 4 + 2], d3 * inv * onw[n * 4 + 3]);
    }
  }
}

// 5) down GEMM + fused h2 epilogue  [R10 verbatim]
#define KPA 388
__global__ __launch_bounds__(128) void k_down(const float* __restrict__ hmat,
    const float* __restrict__ xa, const float* __restrict__ xin,
    const float* __restrict__ skip, const float* __restrict__ dw,
    const float* __restrict__ db, float* __restrict__ out) {
  int m0 = blockIdx.x * 16, n0 = blockIdx.y * 32;
  __shared__ float As[16 * KPA];
  __shared__ float Bs[INNER * 32];
  int t = threadIdx.x;
  for (int idx = t; idx < 16 * 96; idx += 128) {
    int r = idx / 96, k4 = idx % 96;
    int s = m0 + r;
    float4 zv = *(const float4*)&xin[s * (2 * INNER) + INNER + 4 * k4];
    float4 hm = *(const float4*)&hmat[s * INNER + 4 * k4];
    float4 xv = *(const float4*)&xa[s * INNER + 4 * k4];
    float4 sk = *(const float4*)&skip[4 * k4];
    float z, sil;
    float4 o;
    z = zv.x; sil = z / (1.0f + __expf(-z)); o.x = (hm.x + sk.x * xv.x) * sil;
    z = zv.y; sil = z / (1.0f + __expf(-z)); o.y = (hm.y + sk.y * xv.y) * sil;
    z = zv.z; sil = z / (1.0f + __expf(-z)); o.z = (hm.z + sk.z * xv.z) * sil;
    z = zv.w; sil = z / (1.0f + __expf(-z)); o.w = (hm.w + sk.w * xv.w) * sil;
    *(float4*)&As[r * KPA + 4 * k4] = o;
  }
  for (int idx = t; idx < 32 * 96; idx += 128) {
    int r = idx / 96, k4 = idx % 96;
    float4 v = *(const float4*)&dw[(n0 + r) * INNER + 4 * k4];
    int rw = r ^ (4 * (k4 & 7));
    Bs[(4 * k4 + 0) * 32 + rw] = v.x;
    Bs[(4 * k4 + 1) * 32 + rw] = v.y;
    Bs[(4 * k4 + 2) * 32 + rw] = v.z;
    Bs[(4 * k4 + 3) * 32 + rw] = v.w;
  }
  __syncthreads();
  int gm = t >> 4, gn = t & 15;
  float acc[2][2];
  #pragma unroll
  for (int i = 0; i < 2; ++i)
    #pragma unroll
    for (int j = 0; j < 2; ++j) acc[i][j] = db[n0 + 2 * gn + j];
  #pragma unroll 4
  for (int kk = 0; kk < INNER; ++kk) {
    int nk = 4 * ((kk >> 2) & 7);
    float a0 = As[(2 * gm) * KPA + kk];
    float a1 = As[(2 * gm + 1) * KPA + kk];
    float2 bv = *(const float2*)&Bs[kk * 32 + ((2 * gn) ^ nk)];
    acc[0][0] += a0 * bv.x; acc[0][1] += a0 * bv.y;
    acc[1][0] += a1 * bv.x; acc[1][1] += a1 * bv.y;
  }
  #pragma unroll
  for (int i = 0; i < 2; ++i)
    *(float2*)&out[(m0 + 2 * gm + i) * DIM + n0 + 2 * gn] =
        make_float2(acc[i][0], acc[i][1]);
}

extern "C" void kernel_launch(void* const* d_in, const int* in_sizes, int n_in,
                              void* d_out, int out_size, void* d_ws, size_t ws_size,
                              hipStream_t stream) {
  const float* x      = (const float*)d_in[0];
  const float* ln_w   = (const float*)d_in[2];
  const float* ln_b   = (const float*)d_in[3];
  const float* up_w   = (const float*)d_in[4];
  const float* up_b   = (const float*)d_in[5];
  const float* q_w    = (const float*)d_in[8];
  const float* q_b    = (const float*)d_in[9];
  const float* k_w    = (const float*)d_in[10];
  const float* k_b    = (const float*)d_in[11];
  const float* v_w    = (const float*)d_in[12];
  const float* v_b    = (const float*)d_in[13];
  const float* conv_w = (const float*)d_in[14];
  const float* conv_b = (const float*)d_in[15];
  const float* ig_w   = (const float*)d_in[16];
  const float* ig_b   = (const float*)d_in[17];
  const float* fg_w   = (const float*)d_in[18];
  const float* fg_b   = (const float*)d_in[19];
  const float* onorm_w= (const float*)d_in[20];
  const float* skip   = (const float*)d_in[21];
  const float* down_w = (const float*)d_in[22];
  const float* down_b = (const float*)d_in[23];
  float* out = (float*)d_out;

  float* ws     = (float*)d_ws;
  float* xinner = ws;                       // 576*768
  float* xa     = xinner + SEQ * 2 * INNER; // 576*384
  float* ginT   = xa + SEQ * INNER;         // 1152*576
  float* pig    = ginT + GIN * SEQ;         // 4*96*576
  float* pfg    = pig + GKS * NHEAD * SEQ;  // 4*96*576
  float* hbuf   = pfg + GKS * NHEAD * SEQ;  // 576*384

  k_up   <<<dim3(9, 24), 256, 0, stream>>>(x, ln_w, ln_b, up_w, up_b, xinner);
  k_cqkv <<<SEQ, 384, 0, stream>>>(xinner, conv_w, conv_b,
                                   q_w, q_b, k_w, k_b, v_w, v_b, xa, ginT);
  k_gates<<<dim3(6, 9, GKS), 256, 0, stream>>>(ginT, ig_w, fg_w, pig, pfg);
  k_mlstm<<<dim3(NHEAD, 2), 576, 0, stream>>>(ginT, pig, pfg, ig_b, fg_b, onorm_w, hbuf);
  k_down <<<dim3(36, 6), 128, 0, stream>>>(hbuf, xa, xinner, skip, down_w, down_b, out);
}

// Round 12
// 92.356 us; speedup vs baseline: 1.4734x; 1.0988x over previous
//
#include <hip/hip_runtime.h>
#include <math.h>

#define SEQ 576
#define DIM 192
#define INNER 384
#define NHEAD 96
#define HS 24
#define WSZ 24
#define GKS 4

// 1) fused LayerNorm + up-proj GEMM  [R10 verbatim]
__global__ __launch_bounds__(256) void k_up(const float* __restrict__ x,
    const float* __restrict__ lnw, const float* __restrict__ lnb,
    const float* __restrict__ w, const float* __restrict__ b,
    float* __restrict__ out) {
  int m0 = blockIdx.x * 64, n0 = blockIdx.y * 32;
  __shared__ float As[DIM * 64];
  __shared__ float Bs[DIM * 32];
  __shared__ float mu[64], inv[64], ps[192];
  int t = threadIdx.x;
  for (int idx = t; idx < 64 * 48; idx += 256) {
    int r = idx / 48, k4 = idx % 48;
    float4 v = *(const float4*)&x[(m0 + r) * DIM + 4 * k4];
    int rw = r ^ (4 * (k4 & 15));
    As[(4 * k4 + 0) * 64 + rw] = v.x;
    As[(4 * k4 + 1) * 64 + rw] = v.y;
    As[(4 * k4 + 2) * 64 + rw] = v.z;
    As[(4 * k4 + 3) * 64 + rw] = v.w;
  }
  for (int idx = t; idx < 32 * 48; idx += 256) {
    int r = idx / 48, k4 = idx % 48;
    float4 v = *(const float4*)&w[(n0 + r) * DIM + 4 * k4];
    int rw = r ^ (4 * (k4 & 7));
    Bs[(4 * k4 + 0) * 32 + rw] = v.x;
    Bs[(4 * k4 + 1) * 32 + rw] = v.y;
    Bs[(4 * k4 + 2) * 32 + rw] = v.z;
    Bs[(4 * k4 + 3) * 32 + rw] = v.w;
  }
  __syncthreads();
  if (t < 192) {
    int r = t % 64, ph = t / 64;
    float s_ = 0.f;
    #pragma unroll 8
    for (int k = ph * 64; k < ph * 64 + 64; ++k)
      s_ += As[k * 64 + (r ^ (4 * ((k >> 2) & 15)))];
    ps[t] = s_;
  }
  __syncthreads();
  if (t < 64) mu[t] = (ps[t] + ps[64 + t] + ps[128 + t]) * (1.0f / DIM);
  __syncthreads();
  if (t < 192) {
    int r = t % 64, ph = t / 64;
    float m_ = mu[r], s_ = 0.f;
    #pragma unroll 8
    for (int k = ph * 64; k < ph * 64 + 64; ++k) {
      float d = As[k * 64 + (r ^ (4 * ((k >> 2) & 15)))] - m_;
      s_ += d * d;
    }
    ps[t] = s_;
  }
  __syncthreads();
  if (t < 64) inv[t] = rsqrtf((ps[t] + ps[64 + t] + ps[128 + t]) * (1.0f / DIM) + 1e-5f);
  __syncthreads();
  for (int idx = t; idx < 64 * DIM; idx += 256) {
    int k = idx >> 6, r0 = idx & 63;
    int m = r0 ^ (4 * ((k >> 2) & 15));
    As[idx] = (As[idx] - mu[m]) * inv[m] * lnw[k] + lnb[k];
  }
  __syncthreads();
  int gm = t >> 4, gn = t & 15;
  float acc[4][2];
  #pragma unroll
  for (int i = 0; i < 4; ++i)
    #pragma unroll
    for (int j = 0; j < 2; ++j) acc[i][j] = b[n0 + 2 * gn + j];
  #pragma unroll 4
  for (int kk = 0; kk < DIM; ++kk) {
    int mk = (kk >> 2) & 15, nk = 4 * ((kk >> 2) & 7);
    float4 a = *(const float4*)&As[kk * 64 + 4 * (gm ^ mk)];
    float2 bv = *(const float2*)&Bs[kk * 32 + ((2 * gn) ^ nk)];
    acc[0][0] += a.x * bv.x; acc[0][1] += a.x * bv.y;
    acc[1][0] += a.y * bv.x; acc[1][1] += a.y * bv.y;
    acc[2][0] += a.z * bv.x; acc[2][1] += a.z * bv.y;
    acc[3][0] += a.w * bv.x; acc[3][1] += a.w * bv.y;
  }
  #pragma unroll
  for (int i = 0; i < 4; ++i)
    *(float2*)&out[(m0 + 4 * gm + i) * (2 * INNER) + n0 + 2 * gn] =
        make_float2(acc[i][0], acc[i][1]);
}

// 2) conv3x3+SiLU -> xa (row-major), xaT, xmT (transposed); plus W_eff fold.
//    Block per token (576 x 384 thr); blocks 0..191 also compute W_eff row bid.
__global__ __launch_bounds__(384) void k_cqkv(const float* __restrict__ xin,
    const float* __restrict__ cw, const float* __restrict__ cb,
    const float* __restrict__ igw, const float* __restrict__ fgw,
    const float* __restrict__ qw, const float* __restrict__ kw,
    const float* __restrict__ vw,
    float* __restrict__ xa, float* __restrict__ xaT,
    float* __restrict__ xmT, float* __restrict__ weff) {
  int s = blockIdx.x, t = threadIdx.x;
  int h = s / WSZ, wc = s % WSZ;
  float acc = cb[t];
  #pragma unroll
  for (int kh = 0; kh < 3; ++kh) {
    int hh = h + kh - 1;
    if (hh < 0 || hh >= HS) continue;
    #pragma unroll
    for (int kw2 = 0; kw2 < 3; ++kw2) {
      int ww = wc + kw2 - 1;
      if (ww < 0 || ww >= WSZ) continue;
      acc += xin[(hh * WSZ + ww) * (2 * INNER) + t] * cw[t * 9 + kh * 3 + kw2];
    }
  }
  float sil = acc / (1.0f + __expf(-acc));
  xa[s * INNER + t] = sil;
  xaT[t * SEQ + s] = sil;
  xmT[t * SEQ + s] = xin[s * (2 * INNER) + t];
  // W_eff[r][0..767]: fold qkv block-diagonal into gate weights
  if (s < 192) {
    const float* wg = (s < NHEAD) ? (igw + s * 1152) : (fgw + (s - NHEAD) * 1152);
    for (int cp = t; cp < 768; cp += 384) {
      float wv = 0.f;
      if (cp < 384) {
        int n = cp >> 2, j = cp & 3;
        #pragma unroll
        for (int o = 0; o < 4; ++o)
          wv += wg[4 * n + o] * qw[n * 16 + o * 4 + j]
              + wg[384 + 4 * n + o] * kw[n * 16 + o * 4 + j];
      } else {
        int c2 = cp - 384;
        int n = c2 >> 2, j = c2 & 3;
        #pragma unroll
        for (int o = 0; o < 4; ++o)
          wv += wg[768 + 4 * n + o] * vw[n * 16 + o * 4 + j];
      }
      weff[s * 768 + cp] = wv;
    }
  }
}

// 3) gate GEMM: C[192,576] = W_eff[192,768] @ [xaT;xmT], K-split 4 x 192.
//    grid (6,9,4), 256 thr, 2m x 4n per thread, LDS 73.5KB -> 2 blocks/CU.
#define GBK 192
__global__ __launch_bounds__(256) void k_gates(const float* __restrict__ gT,
    const float* __restrict__ weff,
    float* __restrict__ pig, float* __restrict__ pfg) {
  int m0 = blockIdx.x * 32, s0 = blockIdx.y * 64, ksl = blockIdx.z;
  int k0 = ksl * GBK;
  const float* wb = weff + m0 * 768;
  __shared__ float Ws[GBK * 32];
  __shared__ float Gs[GBK * 64];
  int t = threadIdx.x;
  for (int idx = t; idx < 32 * 48; idx += 256) {
    int r = idx / 48, k4 = idx % 48;
    float4 v = *(const float4*)&wb[r * 768 + k0 + 4 * k4];
    int rw = r ^ (4 * (k4 & 7));
    Ws[(4 * k4 + 0) * 32 + rw] = v.x;
    Ws[(4 * k4 + 1) * 32 + rw] = v.y;
    Ws[(4 * k4 + 2) * 32 + rw] = v.z;
    Ws[(4 * k4 + 3) * 32 + rw] = v.w;
  }
  for (int idx = t; idx < GBK * 16; idx += 256) {
    int kk = idx / 16, s4 = idx % 16;
    *(float4*)&Gs[kk * 64 + 4 * s4] =
        *(const float4*)&gT[(k0 + kk) * SEQ + s0 + 4 * s4];
  }
  __syncthreads();
  int gm = t >> 4, gn = t & 15;
  float acc[2][4] = {{0.f,0.f,0.f,0.f},{0.f,0.f,0.f,0.f}};
  #pragma unroll 4
  for (int kk = 0; kk < GBK; ++kk) {
    int nk = 4 * ((kk >> 2) & 7);
    float2 wv = *(const float2*)&Ws[kk * 32 + ((2 * gm) ^ nk)];
    float4 gv = *(const float4*)&Gs[kk * 64 + 4 * gn];
    acc[0][0] += wv.x * gv.x; acc[0][1] += wv.x * gv.y;
    acc[0][2] += wv.x * gv.z; acc[0][3] += wv.x * gv.w;
    acc[1][0] += wv.y * gv.x; acc[1][1] += wv.y * gv.y;
    acc[1][2] += wv.y * gv.z; acc[1][3] += wv.y * gv.w;
  }
  #pragma unroll
  for (int i = 0; i < 2; ++i) {
    int mm = m0 + 2 * gm + i;
    float* dst = (mm < NHEAD) ? (pig + ksl * NHEAD * SEQ + mm * SEQ)
                              : (pfg + ksl * NHEAD * SEQ + (mm - NHEAD) * SEQ);
    *(float4*)&dst[s0 + 4 * gn] =
        make_float4(acc[i][0], acc[i][1], acc[i][2], acc[i][3]);
  }
}

// 4) mLSTM v3: self-computes q/k/v from xaT/xmT, bias-dot, shuffle scans,
//    4-row x 8-col triangular accumulate.  grid (96,2), 576 thr.
__global__ __launch_bounds__(576) void k_mlstm(const float* __restrict__ xaT,
    const float* __restrict__ xmT,
    const float* __restrict__ pig, const float* __restrict__ pfg,
    const float* __restrict__ igw, const float* __restrict__ fgw,
    const float* __restrict__ igb, const float* __restrict__ fgb,
    const float* __restrict__ qw, const float* __restrict__ kw,
    const float* __restrict__ vw,
    const float* __restrict__ qb, const float* __restrict__ kb,
    const float* __restrict__ vb,
    const float* __restrict__ onw, float* __restrict__ hout) {
  int n = blockIdx.x, hh = blockIdx.y, t = threadIdx.x;
  int base = 288 * hh;
  int cnt2 = base + 288;
  __shared__ float ksm[SEQ * 4], vsm[SEQ * 4], esm[SEQ];
  __shared__ float qsm[288 * 4];
  __shared__ float lfcs[SEQ], pms[SEQ];
  __shared__ float wsum[16], wmax[16], bdi[16], bdf[16];
  const int H4 = NHEAD * SEQ;
  int lane = t & 63, w = t >> 6;
  // --- bias-dot: Sum_c gatew[n][c]*qkvb[c], all 576 threads, 2 c's each ---
  {
    float b1 = (t < 384) ? qb[t] : kb[t - 384];
    float b2 = (t < 192) ? kb[192 + t] : vb[t - 192];
    float w1 = igw[n * 1152 + t], w2 = igw[n * 1152 + 576 + t];
    float f1 = fgw[n * 1152 + t], f2 = fgw[n * 1152 + 576 + t];
    float pi = w1 * b1 + w2 * b2;
    float pf = f1 * b1 + f2 * b2;
    #pragma unroll
    for (int o2 = 32; o2 > 0; o2 >>= 1) {
      pi += __shfl_down(pi, o2);
      pf += __shfl_down(pf, o2);
    }
    if (lane == 0) { bdi[w] = pi; bdf[w] = pf; }
  }
  float psi = 0.f, psf = 0.f;
  if (t < cnt2) {
    // self-compute q,k,v for head n at token t
    const float* xan = xaT + 4 * n * SEQ;
    float a0 = xan[t], a1 = xan[SEQ + t], a2 = xan[2 * SEQ + t], a3 = xan[3 * SEQ + t];
    const float* xmn = xmT + 4 * n * SEQ;
    float m0_ = xmn[t], m1_ = xmn[SEQ + t], m2_ = xmn[2 * SEQ + t], m3_ = xmn[3 * SEQ + t];
    #pragma unroll
    for (int o = 0; o < 4; ++o) {
      float kv = kb[4 * n + o] + kw[n * 16 + o * 4 + 0] * a0 + kw[n * 16 + o * 4 + 1] * a1
               + kw[n * 16 + o * 4 + 2] * a2 + kw[n * 16 + o * 4 + 3] * a3;
      ksm[t * 4 + o] = kv * 0.5f;
      vsm[t * 4 + o] = vb[4 * n + o] + vw[n * 16 + o * 4 + 0] * m0_ + vw[n * 16 + o * 4 + 1] * m1_
               + vw[n * 16 + o * 4 + 2] * m2_ + vw[n * 16 + o * 4 + 3] * m3_;
    }
    if (t >= base) {
      int r = t - base;
      #pragma unroll
      for (int o = 0; o < 4; ++o)
        qsm[r * 4 + o] = qb[4 * n + o] + qw[n * 16 + o * 4 + 0] * a0 + qw[n * 16 + o * 4 + 1] * a1
                 + qw[n * 16 + o * 4 + 2] * a2 + qw[n * 16 + o * 4 + 3] * a3;
    }
    int off = n * SEQ + t;
    psi = pig[off] + pig[off + H4] + pig[off + 2 * H4] + pig[off + 3 * H4];
    psf = pfg[off] + pfg[off + H4] + pfg[off + 2 * H4] + pfg[off + 3 * H4];
  }
  __syncthreads();
  float bdI = bdi[0] + bdi[1] + bdi[2] + bdi[3] + bdi[4] + bdi[5] + bdi[6] + bdi[7] + bdi[8];
  float bdF = bdf[0] + bdf[1] + bdf[2] + bdf[3] + bdf[4] + bdf[5] + bdf[6] + bdf[7] + bdf[8];
  float ai = 0.f, lf = 0.f;
  if (t < cnt2) {
    ai = igb[n] + bdI + psi;
    float af = fgb[n] + bdF + psf;
    lf = (af >= 0.f) ? -log1pf(expf(-af)) : (af - log1pf(expf(af)));
  }
  // --- inclusive sum scan of lf ---
  float v = (t < cnt2) ? lf : 0.f;
  #pragma unroll
  for (int o2 = 1; o2 < 64; o2 <<= 1) {
    float u = __shfl_up(v, o2);
    if (lane >= o2) v += u;
  }
  if (lane == 63) wsum[w] = v;
  __syncthreads();
  if (t < 16) {
    float sv = (t < 9) ? wsum[t] : 0.f;
    #pragma unroll
    for (int o2 = 1; o2 < 16; o2 <<= 1) {
      float u = __shfl_up(sv, o2);
      if (t >= o2) sv += u;
    }
    wsum[t] = sv;
  }
  __syncthreads();
  float lfc = v + ((w > 0) ? wsum[w - 1] : 0.f);
  float e = ai - lfc;
  // --- inclusive max scan of e ---
  float m = (t < cnt2) ? e : -3.0e38f;
  #pragma unroll
  for (int o2 = 1; o2 < 64; o2 <<= 1) {
    float u = __shfl_up(m, o2);
    if (lane >= o2) m = fmaxf(m, u);
  }
  if (lane == 63) wmax[w] = m;
  __syncthreads();
  if (t < 16) {
    float sv = (t < 9) ? wmax[t] : -3.0e38f;
    #pragma unroll
    for (int o2 = 1; o2 < 16; o2 <<= 1) {
      float u = __shfl_up(sv, o2);
      if (t >= o2) sv = fmaxf(sv, u);
    }
    wmax[t] = sv;
  }
  __syncthreads();
  float pm = (w > 0) ? fmaxf(m, wmax[w - 1]) : m;
  if (t < cnt2) {
    esm[t] = e;
    lfcs[t] = lfc;
    pms[t] = pm;
  }
  __syncthreads();
  // --- triangular accumulate: thread (rq, cq), rows 4rq.., col-chunk cq/8 ---
  int rq = t >> 3, cq = t & 7;
  int s0 = base + 4 * rq;
  int N = s0 + 4;
  float pmv[4], qv[4][4];
  #pragma unroll
  for (int i = 0; i < 4; ++i) {
    pmv[i] = pms[s0 + i];
    *(float4*)&qv[i][0] = *(float4*)&qsm[(4 * rq + i) * 4];
  }
  int ch = (N + 7) >> 3;
  int lo = cq * ch, hi = min(lo + ch, N);
  float cs[4] = {0.f, 0.f, 0.f, 0.f};
  float hv[4][4];
  #pragma unroll
  for (int i = 0; i < 4; ++i)
    #pragma unroll
    for (int j = 0; j < 4; ++j) hv[i][j] = 0.f;
  for (int tt = lo; tt < hi; ++tt) {
    float e3 = esm[tt];
    float4 kv = *(const float4*)&ksm[tt * 4];
    float4 vv = *(const float4*)&vsm[tt * 4];
    #pragma unroll
    for (int i = 0; i < 4; ++i) {
      if (tt <= s0 + i) {
        float d = __expf(e3 - pmv[i]);
        float c = (qv[i][0] * kv.x + qv[i][1] * kv.y +
                   qv[i][2] * kv.z + qv[i][3] * kv.w) * d;
        cs[i] += c;
        hv[i][0] += c * vv.x; hv[i][1] += c * vv.y;
        hv[i][2] += c * vv.z; hv[i][3] += c * vv.w;
      }
    }
  }
  #pragma unroll
  for (int o2 = 4; o2 > 0; o2 >>= 1) {
    #pragma unroll
    for (int i = 0; i < 4; ++i) {
      cs[i] += __shfl_down(cs[i], o2);
      hv[i][0] += __shfl_down(hv[i][0], o2);
      hv[i][1] += __shfl_down(hv[i][1], o2);
      hv[i][2] += __shfl_down(hv[i][2], o2);
      hv[i][3] += __shfl_down(hv[i][3], o2);
    }
  }
  if (cq == 0) {
    #pragma unroll
    for (int i = 0; i < 4; ++i) {
      int s = s0 + i;
      float mxv = lfcs[s] + pmv[i];
      float norm = fmaxf(fabsf(cs[i]), __expf(-mxv)) + 1e-6f;
      float rr = 1.0f / norm;
      float h0 = hv[i][0] * rr, h1 = hv[i][1] * rr;
      float h2 = hv[i][2] * rr, h3 = hv[i][3] * rr;
      float mu = (h0 + h1 + h2 + h3) * 0.25f;
      float d0 = h0 - mu, d1 = h1 - mu, d2 = h2 - mu, d3 = h3 - mu;
      float var = (d0 * d0 + d1 * d1 + d2 * d2 + d3 * d3) * 0.25f;
      float inv = rsqrtf(var + 1e-5f);
      *(float4*)&hout[s * INNER + n * 4] = make_float4(
          d0 * inv * onw[n * 4 + 0], d1 * inv * onw[n * 4 + 1],
          d2 * inv * onw[n * 4 + 2], d3 * inv * onw[n * 4 + 3]);
    }
  }
}

// 5) down GEMM + fused h2 epilogue  [R10 verbatim]
#define KPA 388
__global__ __launch_bounds__(128) void k_down(const float* __restrict__ hmat,
    const float* __restrict__ xa, const float* __restrict__ xin,
    const float* __restrict__ skip, const float* __restrict__ dw,
    const float* __restrict__ db, float* __restrict__ out) {
  int m0 = blockIdx.x * 16, n0 = blockIdx.y * 32;
  __shared__ float As[16 * KPA];
  __shared__ float Bs[INNER * 32];
  int t = threadIdx.x;
  for (int idx = t; idx < 16 * 96; idx += 128) {
    int r = idx / 96, k4 = idx % 96;
    int s = m0 + r;
    float4 zv = *(const float4*)&xin[s * (2 * INNER) + INNER + 4 * k4];
    float4 hm = *(const float4*)&hmat[s * INNER + 4 * k4];
    float4 xv = *(const float4*)&xa[s * INNER + 4 * k4];
    float4 sk = *(const float4*)&skip[4 * k4];
    float z, sil;
    float4 o;
    z = zv.x; sil = z / (1.0f + __expf(-z)); o.x = (hm.x + sk.x * xv.x) * sil;
    z = zv.y; sil = z / (1.0f + __expf(-z)); o.y = (hm.y + sk.y * xv.y) * sil;
    z = zv.z; sil = z / (1.0f + __expf(-z)); o.z = (hm.z + sk.z * xv.z) * sil;
    z = zv.w; sil = z / (1.0f + __expf(-z)); o.w = (hm.w + sk.w * xv.w) * sil;
    *(float4*)&As[r * KPA + 4 * k4] = o;
  }
  for (int idx = t; idx < 32 * 96; idx += 128) {
    int r = idx / 96, k4 = idx % 96;
    float4 v = *(const float4*)&dw[(n0 + r) * INNER + 4 * k4];
    int rw = r ^ (4 * (k4 & 7));
    Bs[(4 * k4 + 0) * 32 + rw] = v.x;
    Bs[(4 * k4 + 1) * 32 + rw] = v.y;
    Bs[(4 * k4 + 2) * 32 + rw] = v.z;
    Bs[(4 * k4 + 3) * 32 + rw] = v.w;
  }
  __syncthreads();
  int gm = t >> 4, gn = t & 15;
  float acc[2][2];
  #pragma unroll
  for (int i = 0; i < 2; ++i)
    #pragma unroll
    for (int j = 0; j < 2; ++j) acc[i][j] = db[n0 + 2 * gn + j];
  #pragma unroll 4
  for (int kk = 0; kk < INNER; ++kk) {
    int nk = 4 * ((kk >> 2) & 7);
    float a0 = As[(2 * gm) * KPA + kk];
    float a1 = As[(2 * gm + 1) * KPA + kk];
    float2 bv = *(const float2*)&Bs[kk * 32 + ((2 * gn) ^ nk)];
    acc[0][0] += a0 * bv.x; acc[0][1] += a0 * bv.y;
    acc[1][0] += a1 * bv.x; acc[1][1] += a1 * bv.y;
  }
  #pragma unroll
  for (int i = 0; i < 2; ++i)
    *(float2*)&out[(m0 + 2 * gm + i) * DIM + n0 + 2 * gn] =
        make_float2(acc[i][0], acc[i][1]);
}

extern "C" void kernel_launch(void* const* d_in, const int* in_sizes, int n_in,
                              void* d_out, int out_size, void* d_ws, size_t ws_size,
                              hipStream_t stream) {
  const float* x      = (const float*)d_in[0];
  const float* ln_w   = (const float*)d_in[2];
  const float* ln_b   = (const float*)d_in[3];
  const float* up_w   = (const float*)d_in[4];
  const float* up_b   = (const float*)d_in[5];
  const float* q_w    = (const float*)d_in[8];
  const float* q_b    = (const float*)d_in[9];
  const float* k_w    = (const float*)d_in[10];
  const float* k_b    = (const float*)d_in[11];
  const float* v_w    = (const float*)d_in[12];
  const float* v_b    = (const float*)d_in[13];
  const float* conv_w = (const float*)d_in[14];
  const float* conv_b = (const float*)d_in[15];
  const float* ig_w   = (const float*)d_in[16];
  const float* ig_b   = (const float*)d_in[17];
  const float* fg_w   = (const float*)d_in[18];
  const float* fg_b   = (const float*)d_in[19];
  const float* onorm_w= (const float*)d_in[20];
  const float* skip   = (const float*)d_in[21];
  const float* down_w = (const float*)d_in[22];
  const float* down_b = (const float*)d_in[23];
  float* out = (float*)d_out;

  float* ws     = (float*)d_ws;
  float* xinner = ws;                       // 576*768
  float* xa     = xinner + SEQ * 2 * INNER; // 576*384
  float* xaT    = xa + SEQ * INNER;         // 384*576
  float* xmT    = xaT + INNER * SEQ;        // 384*576 (contiguous after xaT!)
  float* weff   = xmT + INNER * SEQ;        // 192*768
  float* pig    = weff + 192 * 768;         // 4*96*576
  float* pfg    = pig + GKS * NHEAD * SEQ;  // 4*96*576
  float* hbuf   = pfg + GKS * NHEAD * SEQ;  // 576*384

  k_up   <<<dim3(9, 24), 256, 0, stream>>>(x, ln_w, ln_b, up_w, up_b, xinner);
  k_cqkv <<<SEQ, 384, 0, stream>>>(xinner, conv_w, conv_b, ig_w, fg_w,
                                   q_w, k_w, v_w, xa, xaT, xmT, weff);
  k_gates<<<dim3(6, 9, GKS), 256, 0, stream>>>(xaT, weff, pig, pfg);
  k_mlstm<<<dim3(NHEAD, 2), 576, 0, stream>>>(xaT, xmT, pig, pfg, ig_w, fg_w,
                                              ig_b, fg_b, q_w, k_w, v_w,
                                              q_b, k_b, v_b, onorm_w, hbuf);
  k_down <<<dim3(36, 6), 128, 0, stream>>>(hbuf, xa, xinner, skip, down_w, down_b, out);
}